// Round 7
// baseline (519.636 us; speedup 1.0000x reference)
//
#include <hip/hip_runtime.h>
#include <math.h>

#define B 1024
#define T 512
#define S 48
#define SOS 47
#define TS (T * S)

typedef short short8 __attribute__((ext_vector_type(8)));
typedef float f32x4 __attribute__((ext_vector_type(4)));

// f32 -> bf16 (RNE), values are >= 0 normal/zero here
__device__ __forceinline__ short f2bf(float f) {
    unsigned u = __float_as_uint(f);
    return (short)((u + 0x7FFFu + ((u >> 16) & 1u)) >> 16);
}

// ---------------------------------------------------------------------------
// CRF loss, MFMA formulation. 64 blocks x 1 wave; each wave owns 16 batch
// rows. State dim padded 48->64. Per step t:
//   D[16x48] = Q[16x64] x expT^T      (6x mfma_f32_16x16x32_bf16, B static)
//   Q'       = select(mask, D * exp(emis) * 2^{-e_row}, Q)   [C-layout regs]
//   C_row   += e_row*ln2 on live steps  (exponent stripping; exact, no log)
// C->A layout round trip through LDS: 12x ds_write_b16 + 2x ds_read_b128,
// 1 wave/CU -> no DS contention (r1-r6 showed 4-wave/CU scan pinned at
// ~850-1150 cyc/step regardless of instruction mix). Row stride 144B.
// Emissions: 12 coalesced loads/step, register ring depth 4 (~12KB in
// flight/wave) so vmcnt waits hit 4-step-old loads. bf16 q is safe: full
// f32 exponent range; per-row power-of-2 renorm keeps values near 1.
// ---------------------------------------------------------------------------
__global__ __launch_bounds__(64)
__attribute__((amdgpu_waves_per_eu(1, 1)))
void crf_mfma(const float* __restrict__ feat, const int* __restrict__ states,
              const float* __restrict__ mask, const float* __restrict__ trans,
              float* __restrict__ out) {
    __shared__ __align__(16) short qlds[16 * 72];   // 16 rows x 144B
    __shared__ unsigned short m16[T];               // per-t 16 row-mask bits
    __shared__ float nsum_l[16];
    const int lane = threadIdx.x;
    const int n = lane & 15, quad = lane >> 4;
    const int b0 = blockIdx.x * 16;

    // ---------- numerator + mask16 (lane = row n, time-slice quad) ----------
    {
        const float* fr = feat + (size_t)(b0 + n) * TS;
        const int* str = states + (b0 + n) * T;
        const float* mr = mask + (b0 + n) * T;
        float acc = 0.f;
#pragma unroll 8
        for (int k2 = 0; k2 < T / 4; ++k2) {
            const int t = quad + 4 * k2;
            const int st = str[t];
            const int pv = (t == 0) ? SOS : str[t - 1];
            const float m = mr[t];
            acc += (fr[t * S + st] + trans[st * S + pv]) * m;
            // ballot bit (row + 16*quad) -> four mask16 words per ballot
            const unsigned long long bal = __ballot(m != 0.f);
            if (lane < 4) m16[lane + 4 * k2] = (unsigned short)(bal >> (16 * lane));
        }
        acc += __shfl_xor(acc, 16, 64);
        acc += __shfl_xor(acc, 32, 64);
        if (quad == 0) nsum_l[n] = acc;
    }

    // ---------- B fragments: B[k][n'] = expT[n'][k] = exp(trans[n'][k]) ----
    // layout (16x16x32): n' = lane&15 (+16*nt), k = quad*8 + e (+32*kc)
    short8 Bf[3][2];
#pragma unroll
    for (int nt = 0; nt < 3; ++nt)
#pragma unroll
        for (int kc = 0; kc < 2; ++kc) {
            short8 v;
#pragma unroll
            for (int e = 0; e < 8; ++e) {
                const int k = kc * 32 + quad * 8 + e;
                const float x = (k < S) ? __expf(trans[(nt * 16 + n) * S + k]) : 0.f;
                v[e] = f2bf(x);
            }
            Bf[nt][kc] = v;
        }

    // ---------- init Q: 1.0 at SOS, else 0 (LDS + C-layout regs) ----------
    for (int i = lane; i < 16 * 72; i += 64) qlds[i] = 0;
    if (lane < 16) qlds[lane * 72 + SOS] = (short)0x3F80;   // bf16 1.0
    float qreg[3][4];
#pragma unroll
    for (int nt = 0; nt < 3; ++nt)
#pragma unroll
        for (int r = 0; r < 4; ++r) qreg[nt][r] = 0.f;
    if (n == 15)
#pragma unroll
        for (int r = 0; r < 4; ++r) qreg[2][r] = 1.f;       // col 47

    // per-lane feature bases for rows quad*4+r, column n
    const float* rb[4];
#pragma unroll
    for (int r = 0; r < 4; ++r)
        rb[r] = feat + (size_t)(b0 + quad * 4 + r) * TS + n;

    // emission ring: slot k holds t = tb*4+k (static indices only)
    float ering[4][12];
#pragma unroll
    for (int k = 0; k < 4; ++k)
#pragma unroll
        for (int nt = 0; nt < 3; ++nt)
#pragma unroll
            for (int r = 0; r < 4; ++r)
                ering[k][nt * 4 + r] = rb[r][k * S + nt * 16];

    const int a_base = n * 144 + quad * 16;    // A-read byte offset
    const int w_base = quad * 4 * 72 + n;      // write short-index base
    const int bp_addr = ((lane & 48) | 1) << 2;

    float sc[4] = {1.f, 1.f, 1.f, 1.f};        // pending 2^{-e}
    float eexp[4] = {0.f, 0.f, 0.f, 0.f};      // pending e
    float Cc[4] = {0.f, 0.f, 0.f, 0.f};
    const f32x4 zero4 = {0.f, 0.f, 0.f, 0.f};

#pragma unroll 1
    for (int tb = 0; tb < T / 4; ++tb) {
#pragma unroll
        for (int k = 0; k < 4; ++k) {
            const int t = tb * 4 + k;
            // consume slot k -> E, then re-prime slot k for t+4
            float E[12];
#pragma unroll
            for (int i = 0; i < 12; ++i) E[i] = __expf(ering[k][i]);
            const int tp = (t + 4) & (T - 1);  // wrap: final primes unused
#pragma unroll
            for (int nt = 0; nt < 3; ++nt)
#pragma unroll
                for (int r = 0; r < 4; ++r)
                    ering[k][nt * 4 + r] = rb[r][tp * S + nt * 16];

            const unsigned mm = m16[t];
            // A fragments from LDS (reads precede this step's writes)
            const short8 a0 = *(const short8*)((const char*)qlds + a_base);
            const short8 a1 = *(const short8*)((const char*)qlds + a_base + 64);

            f32x4 d0 = __builtin_amdgcn_mfma_f32_16x16x32_bf16(a0, Bf[0][0], zero4, 0, 0, 0);
            d0 = __builtin_amdgcn_mfma_f32_16x16x32_bf16(a1, Bf[0][1], d0, 0, 0, 0);
            f32x4 d1 = __builtin_amdgcn_mfma_f32_16x16x32_bf16(a0, Bf[1][0], zero4, 0, 0, 0);
            d1 = __builtin_amdgcn_mfma_f32_16x16x32_bf16(a1, Bf[1][1], d1, 0, 0, 0);
            f32x4 d2 = __builtin_amdgcn_mfma_f32_16x16x32_bf16(a0, Bf[2][0], zero4, 0, 0, 0);
            d2 = __builtin_amdgcn_mfma_f32_16x16x32_bf16(a1, Bf[2][1], d2, 0, 0, 0);
            float dv[3][4];
#pragma unroll
            for (int r = 0; r < 4; ++r) { dv[0][r] = d0[r]; dv[1][r] = d1[r]; dv[2][r] = d2[r]; }

            bool lv[4];
#pragma unroll
            for (int r = 0; r < 4; ++r)
                lv[r] = ((mm >> (quad * 4 + r)) & 1u) != 0u;

#pragma unroll
            for (int nt = 0; nt < 3; ++nt)
#pragma unroll
                for (int r = 0; r < 4; ++r) {
                    const float v = dv[nt][r] * E[nt * 4 + r] * sc[r];
                    qreg[nt][r] = lv[r] ? v : qreg[nt][r];   // SELECT, never blend
                    qlds[w_base + r * 72 + nt * 16] = f2bf(qreg[nt][r]);
                }

            // bookkeeping: apply pending exponent, derive next from q[row][1]
#pragma unroll
            for (int r = 0; r < 4; ++r) {
                Cc[r] += lv[r] ? eexp[r] * 0.69314718056f : 0.f;
                const float dr = __int_as_float(
                    __builtin_amdgcn_ds_bpermute(bp_addr, __float_as_int(qreg[0][r])));
                int e = ((__float_as_int(dr) >> 23) & 0xFF) - 127;
                e = min(12, max(-12, e));                    // guards dr==0 startup
                eexp[r] = (float)e;
                sc[r] = __int_as_float((unsigned)(127 - e) << 23);
            }
        }
    }

    // ---------- epilogue: out[b] = C_b + log(sum_i q_b_i) - numer_b ----------
#pragma unroll
    for (int r = 0; r < 4; ++r) {
        float s = qreg[0][r] + qreg[1][r] + qreg[2][r];
        s += __shfl_xor(s, 1, 64);
        s += __shfl_xor(s, 2, 64);
        s += __shfl_xor(s, 4, 64);
        s += __shfl_xor(s, 8, 64);
        if (n == 0) {
            const int row = quad * 4 + r;
            out[b0 + row] = Cc[r] + __logf(s) - nsum_l[row];
        }
    }
}

extern "C" void kernel_launch(void* const* d_in, const int* in_sizes, int n_in,
                              void* d_out, int out_size, void* d_ws, size_t ws_size,
                              hipStream_t stream) {
    const float* feat   = (const float*)d_in[0];   // (B,T,S) f32
    const int*   states = (const int*)d_in[1];     // (B,T) i32
    const float* mask   = (const float*)d_in[2];   // (B,T) f32
    const float* trans  = (const float*)d_in[3];   // (S,S) f32
    float* out = (float*)d_out;                    // (B,) f32

    crf_mfma<<<dim3(B / 16), dim3(64), 0, stream>>>(feat, states, mask, trans, out);
}

// Round 8
// 432.964 us; speedup vs baseline: 1.2002x; 1.2002x over previous
//
#include <hip/hip_runtime.h>
#include <math.h>

#define B 1024
#define T 512
#define S 48
#define SOS 47
#define TS (T * S)
#define R 4                    // batch rows per wave

typedef _Float16 half2v __attribute__((ext_vector_type(2)));
typedef _Float16 half8v __attribute__((ext_vector_type(8)));

__device__ __forceinline__ float rdlane1(float v) {
    return __int_as_float(__builtin_amdgcn_readlane(__float_as_int(v), 1));
}

// ---------------------------------------------------------------------------
// Fused CRF loss. 256 blocks x 1 wave; each wave owns R=4 batch rows.
// Lane i owns state i (48 active). Per row, r6's exact (absmax-0) scheme:
//   t_i = (sum_j expT[i][j] q_j) * E_i,  E = exp(emis)      [f16 dot2]
//   q'_i = t_i * rcp(t_1)   (t_1 = d_1*E_1; E_1 off-chain, d_1 readlane)
//   C    = -log(prod rcp)   tracked as product P with exponent stripping
// WHY 4 rows/wave + 1 block/CU: r1-r6 pinned at 860-1150 cyc/step with 4
// single-wave blocks/CU -- in-order issue exposes every stall of the single
// chain, and DS is shared 4 ways. Four INDEPENDENT row-chains inside one
// wave fill each other's stall slots; the wave owns the whole CU's LDS.
// f16 q safe: fresh renorm keeps spread <= e^10 ~ 22k < 65504.
// ---------------------------------------------------------------------------
__global__ __launch_bounds__(64)
__attribute__((amdgpu_waves_per_eu(1, 1)))
void crf_fused(const float* __restrict__ feat, const int* __restrict__ states,
               const float* __restrict__ mask, const float* __restrict__ trans,
               float* __restrict__ out) {
    __shared__ __align__(16) _Float16 qbuf[R][2][64];
    __shared__ unsigned long long mbits[R][T / 64];   // per-row 512-bit mask
    const int lane = threadIdx.x;
    const int elane = (lane < S) ? lane : 0;          // lanes 48-63 shadow 0
    const int b0 = blockIdx.x * R;

    // ---- numerator + mask bitmaps, per row (overlaps expT setup) ----
    float nsum[R];
#pragma unroll
    for (int r = 0; r < R; ++r) {
        const float* fr = feat + (size_t)(b0 + r) * TS;
        const int* str = states + (b0 + r) * T;
        const float* mr = mask + (b0 + r) * T;
        float acc = 0.f;
#pragma unroll
        for (int k2 = 0; k2 < T / 64; ++k2) {
            const int t = lane + 64 * k2;
            const int st = str[t];
            const int pv = (t == 0) ? SOS : str[t - 1];
            const float m = mr[t];
            acc += (fr[t * S + st] + trans[st * S + pv]) * m;
            const unsigned long long bal = __ballot(m != 0.f);
            if (lane == 0) mbits[r][k2] = bal;
        }
#pragma unroll
        for (int off = 32; off > 0; off >>= 1) acc += __shfl_xor(acc, off, 64);
        nsum[r] = acc;
    }

    // ---- expT row for this lane as f16 pairs; exp(-9999) -> exact 0 ----
    half2v eT[S / 2];
    {
        const float4* t4 = (const float4*)(trans + elane * S);
#pragma unroll
        for (int j4 = 0; j4 < S / 4; ++j4) {
            const float4 tv = t4[j4];
            const float e0 = (lane < S) ? __expf(tv.x) : 0.f;
            const float e1 = (lane < S) ? __expf(tv.y) : 0.f;
            const float e2 = (lane < S) ? __expf(tv.z) : 0.f;
            const float e3 = (lane < S) ? __expf(tv.w) : 0.f;
            eT[2 * j4 + 0] = half2v{(_Float16)e0, (_Float16)e1};
            eT[2 * j4 + 1] = half2v{(_Float16)e2, (_Float16)e3};
        }
    }

    // ---- scan state (per row) ----
    float q[R], P[R];
    int cexp[R];
    const float* frp[R];
#pragma unroll
    for (int r = 0; r < R; ++r) {
        q[r] = (lane == SOS) ? 1.f : 0.f;
        qbuf[r][0][lane] = (_Float16)q[r];
        P[r] = 1.f;
        cexp[r] = 0;
        frp[r] = feat + (size_t)(b0 + r) * TS + elane;
    }

    // emission ring, depth 8 per row (slot k consumed then refilled for t+8)
    float ering[R][8];
#pragma unroll
    for (int r = 0; r < R; ++r)
#pragma unroll
        for (int k = 0; k < 8; ++k) ering[r][k] = frp[r][k * S];

#pragma unroll 1
    for (int tb = 0; tb < T / 8; ++tb) {
        unsigned mby[R];
#pragma unroll
        for (int r = 0; r < R; ++r)
            mby[r] = ((const unsigned char*)&mbits[r][0])[tb];
#pragma unroll
        for (int k = 0; k < 8; ++k) {
            const int t = tb * 8 + k;
            const int tp = (t + 8) & (T - 1);      // wrap: tail refills unused
            float E[R], E1[R], d[R];
            // phase 1: all rows' E factors + lane-1 scalars (off-chain)
#pragma unroll
            for (int r = 0; r < R; ++r) {
                const float emis = ering[r][k];
                E[r] = __expf(emis);
                E1[r] = __expf(rdlane1(emis));
                ering[r][k] = frp[r][tp * S];      // refill 8 steps ahead
            }
            // phase 2: all rows' broadcast dots (independent chains)
#pragma unroll
            for (int r = 0; r < R; ++r) {
                const half8v* qb = (const half8v*)&qbuf[r][k & 1][0];
                float ax = 0.f, ay = 0.f, az = 0.f, aw = 0.f;
#pragma unroll
                for (int c = 0; c < 6; ++c) {
                    const half8v h = qb[c];
                    const half2v p0 = __builtin_shufflevector(h, h, 0, 1);
                    const half2v p1 = __builtin_shufflevector(h, h, 2, 3);
                    const half2v p2 = __builtin_shufflevector(h, h, 4, 5);
                    const half2v p3 = __builtin_shufflevector(h, h, 6, 7);
                    ax = __builtin_amdgcn_fdot2(eT[4 * c + 0], p0, ax, false);
                    ay = __builtin_amdgcn_fdot2(eT[4 * c + 1], p1, ay, false);
                    az = __builtin_amdgcn_fdot2(eT[4 * c + 2], p2, az, false);
                    aw = __builtin_amdgcn_fdot2(eT[4 * c + 3], p3, aw, false);
                }
                d[r] = (ax + ay) + (az + aw);
            }
            // phase 3: renorm tails (short chains, interleave across rows)
#pragma unroll
            for (int r = 0; r < R; ++r) {
                const float t1 = rdlane1(d[r]) * E1[r];   // lane1 dot > 0
                const float rc = __builtin_amdgcn_rcpf(t1);
                const float qn = (d[r] * E[r]) * rc;
                const bool live = ((mby[r] >> k) & 1u) != 0u;
                q[r] = live ? qn : q[r];                  // SELECT, never blend
                qbuf[r][(k + 1) & 1][lane] = (_Float16)q[r];
                // off-chain: normalizer product, exponent-stripped
                P[r] *= live ? rc : 1.f;
                const int pb = __float_as_int(P[r]);
                cexp[r] += (pb >> 23) - 127;
                P[r] = __int_as_float((pb & 0x007FFFFF) | 0x3F800000);
            }
        }
    }

    // ---- epilogue: denom_r = -log(P*2^cexp) + log(sum_i q_i) ----
#pragma unroll
    for (int r = 0; r < R; ++r) {
        float ps = q[r];                            // lanes >= 48 hold 0
#pragma unroll
        for (int off = 32; off > 0; off >>= 1) ps += __shfl_xor(ps, off, 64);
        if (lane == 0) {
            const float C = -((float)cexp[r] * 0.69314718056f + __logf(P[r]));
            out[b0 + r] = C + __logf(ps) - nsum[r];
        }
    }
}

extern "C" void kernel_launch(void* const* d_in, const int* in_sizes, int n_in,
                              void* d_out, int out_size, void* d_ws, size_t ws_size,
                              hipStream_t stream) {
    const float* feat   = (const float*)d_in[0];   // (B,T,S) f32
    const int*   states = (const int*)d_in[1];     // (B,T) i32
    const float* mask   = (const float*)d_in[2];   // (B,T) f32
    const float* trans  = (const float*)d_in[3];   // (S,S) f32
    float* out = (float*)d_out;                    // (B,) f32

    crf_fused<<<dim3(B / R), dim3(64), 0, stream>>>(feat, states, mask, trans, out);
}